// Round 2
// baseline (10401.192 us; speedup 1.0000x reference)
//
#include <hip/hip_runtime.h>
#include <hip/hip_bf16.h>
#include <math.h>

#define NB 32
#define NS 4096
#define ND 256
#define NHOP 10
#define EPSBN 1e-5f
#define NEG_SLOPE 0.01f

// ---------------- workspace layout (bytes) ----------------
static const size_t OFF_BUFA  = 0;
static const size_t OFF_BUFB  = OFF_BUFA + (size_t)NB*NS*ND*4;   // 134217728
static const size_t OFF_E     = OFF_BUFB + (size_t)NB*NS*ND*4;   // 268435456
static const size_t OFF_Q     = OFF_E    + (size_t)NB*NS*4;
static const size_t OFF_OPART = OFF_Q    + (size_t)NB*ND*4;
static const size_t OFF_WT    = OFF_OPART+ (size_t)NB*32*ND*4;
static const size_t OFF_SCALE = OFF_WT   + (size_t)1280*ND*4;
static const size_t OFF_SHIFT = OFF_SCALE+ (size_t)ND*4;
static const size_t OFF_RMAX  = OFF_SHIFT+ (size_t)ND*4;
static const size_t OFF_RINV  = OFF_RMAX + (size_t)NB*4;
static const size_t OFF_HALT  = OFF_RINV + (size_t)NB*4;
static const size_t OFF_RUN   = OFF_HALT + (size_t)NB*4;

// ---------------- init: pack W, BN affine, q, halted, running ----------------
__global__ void k_init(const float* __restrict__ conv_w, const float* __restrict__ conv_b,
                       const float* __restrict__ bn_gamma, const float* __restrict__ bn_beta,
                       const float* __restrict__ bn_mean, const float* __restrict__ bn_var,
                       const float* __restrict__ query,
                       float* __restrict__ Wt, float* __restrict__ scale, float* __restrict__ shift,
                       float* __restrict__ q, int* __restrict__ halted, int* __restrict__ running)
{
    int idx = blockIdx.x * 256 + threadIdx.x;
    if (idx < 1280 * 256) {
        // Wt[(t*256+din)*256 + dout] = conv_w[dout, din, t]
        int dout = idx & 255;
        int k    = idx >> 8;
        int din  = k & 255;
        int t    = k >> 8;
        Wt[idx] = conv_w[dout * 1280 + din * 5 + t];
    }
    if (idx < NB * ND) q[idx] = query[idx & (ND - 1)];
    if (idx < ND) {
        float a = bn_gamma[idx] * rsqrtf(bn_var[idx] + EPSBN);
        scale[idx] = a;
        shift[idx] = (conv_b[idx] - bn_mean[idx]) * a + bn_beta[idx];
    }
    if (idx < NB) halted[idx] = 0;
    if (idx == 0) running[0] = 1;
}

// ---------------- K1: e[b,s] = dot(xc[b,s,:], q[b,:]), mask -> -inf ----------------
__global__ void k_attn(const float* __restrict__ xc, const float* __restrict__ q,
                       const int* __restrict__ mask, float* __restrict__ e)
{
    int row  = blockIdx.x * 4 + (threadIdx.x >> 6);   // [0, NB*NS)
    int lane = threadIdx.x & 63;
    int b    = row >> 12;
    float4 xv = *(const float4*)(xc + (long)row * ND + (lane << 2));
    float4 qv = *(const float4*)(q + b * ND + (lane << 2));
    float v = xv.x * qv.x + xv.y * qv.y + xv.z * qv.z + xv.w * qv.w;
    #pragma unroll
    for (int off = 32; off; off >>= 1) v += __shfl_xor(v, off, 64);
    if (lane == 0) e[row] = (mask[row] != 0) ? -INFINITY : v;
}

// ---------------- K2: per-b softmax stats; block0 computes running flag ----------------
__global__ void k_stats(const float* __restrict__ e, float* __restrict__ rmax,
                        float* __restrict__ rinv, const int* __restrict__ halted,
                        int* __restrict__ running)
{
    __shared__ float sm[256];
    int b = blockIdx.x, tid = threadIdx.x;
    float m = -INFINITY;
    for (int s = tid; s < NS; s += 256) m = fmaxf(m, e[b * NS + s]);
    sm[tid] = m; __syncthreads();
    for (int off = 128; off; off >>= 1) {
        if (tid < off) sm[tid] = fmaxf(sm[tid], sm[tid + off]);
        __syncthreads();
    }
    float bm = sm[0]; __syncthreads();
    float sum = 0.f;
    for (int s = tid; s < NS; s += 256) sum += expf(e[b * NS + s] - bm);
    sm[tid] = sum; __syncthreads();
    for (int off = 128; off; off >>= 1) {
        if (tid < off) sm[tid] += sm[tid + off];
        __syncthreads();
    }
    if (tid == 0) { rmax[b] = bm; rinv[b] = 1.0f / sm[0]; }
    if (b == 0 && tid < 64) {
        unsigned long long any = __ballot(tid < NB && halted[tid] != 0);
        if (tid == 0) running[0] = (any == 0ull) ? 1 : 0;
    }
}

// ---------------- K3: conv(k=5) + BN + leakyReLU + mask; gated copy when frozen ----------
// block = 512 threads, tile 128 rows x 256 douts, per-thread 8x8
__global__ __launch_bounds__(512) void k_conv(
    const float* __restrict__ xc, float* __restrict__ xn,
    const float* __restrict__ Wt, const float* __restrict__ scale,
    const float* __restrict__ shift, const int* __restrict__ mask,
    const int* __restrict__ running)
{
    const int bb = blockIdx.x >> 5;
    const int s0 = (blockIdx.x & 31) << 7;
    const int tid = threadIdx.x;
    const long base = ((long)bb * NS + s0) * ND;

    if (running[0] == 0) {   // frozen state: xn = xc
        const float4* src = (const float4*)(xc + base);
        float4* dst = (float4*)(xn + base);
        for (int i = tid; i < 128 * 64; i += 512) dst[i] = src[i];
        return;
    }

    __shared__ float A[64][140];   // [din-chunk][row], rows = s0-4 .. s0+131
    const int tr = tid >> 5, tc = tid & 31;
    const int r0 = tr << 3, c0 = tc << 3;

    float acc[8][8];
    #pragma unroll
    for (int i = 0; i < 8; ++i)
        #pragma unroll
        for (int j = 0; j < 8; ++j) acc[i][j] = 0.f;

    for (int kc = 0; kc < 4; ++kc) {
        __syncthreads();
        for (int i = tid; i < 136 * 16; i += 512) {
            int lr = i >> 4, lg = i & 15;
            int s = s0 - 4 + lr;
            float4 v = make_float4(0.f, 0.f, 0.f, 0.f);
            if (s >= 0 && s < NS)
                v = *(const float4*)(xc + ((long)bb * NS + s) * ND + (kc << 6) + (lg << 2));
            A[(lg << 2) + 0][lr] = v.x;
            A[(lg << 2) + 1][lr] = v.y;
            A[(lg << 2) + 2][lr] = v.z;
            A[(lg << 2) + 3][lr] = v.w;
        }
        __syncthreads();

        for (int kk = 0; kk < 64; ++kk) {
            float xr[16];
            #pragma unroll
            for (int j = 0; j < 4; ++j) {
                float4 v = *(const float4*)(&A[kk][r0 + (j << 2)]);
                xr[j * 4 + 0] = v.x; xr[j * 4 + 1] = v.y;
                xr[j * 4 + 2] = v.z; xr[j * 4 + 3] = v.w;
            }
            const float* wp = Wt + ((kc << 6) + kk) * ND + c0;
            #pragma unroll
            for (int t = 0; t < 5; ++t) {
                float4 w0 = *(const float4*)(wp + t * 65536);
                float4 w1 = *(const float4*)(wp + t * 65536 + 4);
                #pragma unroll
                for (int r = 0; r < 8; ++r) {
                    float xv = xr[r + t + 2];   // global row s0+r0+r+t-2
                    acc[r][0] += xv * w0.x; acc[r][1] += xv * w0.y;
                    acc[r][2] += xv * w0.z; acc[r][3] += xv * w0.w;
                    acc[r][4] += xv * w1.x; acc[r][5] += xv * w1.y;
                    acc[r][6] += xv * w1.z; acc[r][7] += xv * w1.w;
                }
            }
        }
    }

    float sc[8], sh[8];
    #pragma unroll
    for (int c = 0; c < 8; ++c) { sc[c] = scale[c0 + c]; sh[c] = shift[c0 + c]; }

    #pragma unroll
    for (int r = 0; r < 8; ++r) {
        int s = s0 + r0 + r;
        int mrow = mask[bb * NS + s];
        float out[8];
        #pragma unroll
        for (int c = 0; c < 8; ++c) {
            float v = acc[r][c] * sc[c] + sh[c];
            v = (v >= 0.f) ? v : NEG_SLOPE * v;
            out[c] = mrow ? 0.f : v;
        }
        float4* dp = (float4*)(xn + ((long)bb * NS + s) * ND + c0);
        dp[0] = make_float4(out[0], out[1], out[2], out[3]);
        dp[1] = make_float4(out[4], out[5], out[6], out[7]);
    }
}

// ---------------- K4: o partials over 128-row chunks ----------------
__global__ void k_opart(const float* __restrict__ xn, const float* __restrict__ e,
                        const float* __restrict__ rmax, const float* __restrict__ rinv,
                        float* __restrict__ o_part)
{
    int b = blockIdx.x >> 5, ch = blockIdx.x & 31;
    int s0 = ch << 7;
    int tid = threadIdx.x;
    __shared__ float p[128];
    if (tid < 128) {
        float ev = e[b * NS + s0 + tid];
        p[tid] = expf(ev - rmax[b]) * rinv[b];   // -inf -> 0
    }
    __syncthreads();
    float acc = 0.f;
    const float* xp = xn + ((long)b * NS + s0) * ND + tid;
    #pragma unroll 4
    for (int j = 0; j < 128; ++j) acc += p[j] * xp[(long)j * ND];
    o_part[(b * 32 + ch) * ND + tid] = acc;
}

// ---------------- K5: reduce o, halt logits, gated q/halted update ----------------
__global__ void k_update(const float* __restrict__ o_part, float* __restrict__ q,
                         const float* __restrict__ halt_w, const float* __restrict__ halt_b,
                         int* __restrict__ halted, const int* __restrict__ running)
{
    int b = blockIdx.x, d = threadIdx.x;
    __shared__ float sh0[256], sh1[256];
    float o = 0.f;
    #pragma unroll
    for (int ch = 0; ch < 32; ++ch) o += o_part[(b * 32 + ch) * ND + d];
    float qd = q[b * ND + d];
    float s1 = o + qd;
    sh0[d] = s1 * halt_w[d];
    sh1[d] = s1 * halt_w[ND + d];
    __syncthreads();
    for (int off = 128; off; off >>= 1) {
        if (d < off) { sh0[d] += sh0[d + off]; sh1[d] += sh1[d + off]; }
        __syncthreads();
    }
    float l0 = sh0[0] + halt_b[0];
    float l1 = sh1[0] + halt_b[1];
    int hOld = halted[b];
    if (running[0]) {
        q[b * ND + d] = o + qd * (1.f - (float)hOld);
        if (d == 0) halted[b] = hOld | ((l1 > l0) ? 1 : 0);
    }
}

// ---------------- K6: q -> d_out ----------------
__global__ void k_copyout(const float* __restrict__ q, float* __restrict__ out)
{
    int idx = blockIdx.x * 256 + threadIdx.x;
    if (idx < NB * ND) out[idx] = q[idx];
}

extern "C" void kernel_launch(void* const* d_in, const int* in_sizes, int n_in,
                              void* d_out, int out_size, void* d_ws, size_t ws_size,
                              hipStream_t stream)
{
    const float* x        = (const float*)d_in[0];
    const int*   mask     = (const int*)  d_in[1];
    const float* query    = (const float*)d_in[2];
    const float* conv_w   = (const float*)d_in[3];
    const float* conv_b   = (const float*)d_in[4];
    const float* bn_gamma = (const float*)d_in[5];
    const float* bn_beta  = (const float*)d_in[6];
    const float* bn_mean  = (const float*)d_in[7];
    const float* bn_var   = (const float*)d_in[8];
    const float* halt_w   = (const float*)d_in[9];
    const float* halt_b   = (const float*)d_in[10];

    char* ws = (char*)d_ws;
    float* bufA   = (float*)(ws + OFF_BUFA);
    float* bufB   = (float*)(ws + OFF_BUFB);
    float* ebuf   = (float*)(ws + OFF_E);
    float* qbuf   = (float*)(ws + OFF_Q);
    float* opart  = (float*)(ws + OFF_OPART);
    float* Wt     = (float*)(ws + OFF_WT);
    float* scale  = (float*)(ws + OFF_SCALE);
    float* shift  = (float*)(ws + OFF_SHIFT);
    float* rmax   = (float*)(ws + OFF_RMAX);
    float* rinv   = (float*)(ws + OFF_RINV);
    int*   halted = (int*)  (ws + OFF_HALT);
    int*   runf   = (int*)  (ws + OFF_RUN);

    k_init<<<1280, 256, 0, stream>>>(conv_w, conv_b, bn_gamma, bn_beta, bn_mean, bn_var,
                                     query, Wt, scale, shift, qbuf, halted, runf);

    for (int h = 0; h < NHOP; ++h) {
        const float* xc = (h == 0) ? x : ((h & 1) ? bufA : bufB);
        float* xo = (h & 1) ? bufB : bufA;

        k_attn  <<<NB * NS / 4, 256, 0, stream>>>(xc, qbuf, mask, ebuf);
        k_stats <<<NB, 256, 0, stream>>>(ebuf, rmax, rinv, halted, runf);
        k_conv  <<<NB * 32, 512, 0, stream>>>(xc, xo, Wt, scale, shift, mask, runf);
        k_opart <<<NB * 32, 256, 0, stream>>>(xo, ebuf, rmax, rinv, opart);
        k_update<<<NB, 256, 0, stream>>>(opart, qbuf, halt_w, halt_b, halted, runf);
    }

    k_copyout<<<NB, 256, 0, stream>>>(qbuf, (float*)d_out);
}

// Round 3
// 2681.225 us; speedup vs baseline: 3.8793x; 3.8793x over previous
//
#include <hip/hip_runtime.h>
#include <hip/hip_bf16.h>
#include <math.h>

#define NB 32
#define NS 4096
#define ND 256
#define NHOP 10
#define EPSBN 1e-5f
#define NEG_SLOPE 0.01f

typedef _Float16 half8 __attribute__((ext_vector_type(8)));
typedef float floatx4 __attribute__((ext_vector_type(4)));

// ---------------- workspace layout (bytes) ----------------
static const size_t SZ_PAIR = (size_t)NB*NS*ND*2;            // 67,108,864 (ushort plane)
static const size_t OFF_HI0 = 0;
static const size_t OFF_LO0 = OFF_HI0 + SZ_PAIR;
static const size_t OFF_HI1 = OFF_LO0 + SZ_PAIR;
static const size_t OFF_LO1 = OFF_HI1 + SZ_PAIR;
static const size_t OFF_E   = OFF_LO1 + SZ_PAIR;             // 268,435,456
static const size_t OFF_Q   = OFF_E   + (size_t)NB*NS*4;
static const size_t OFF_OP  = OFF_Q   + (size_t)NB*ND*4;
static const size_t OFF_WPH = OFF_OP  + (size_t)NB*32*ND*4;
static const size_t OFF_WPL = OFF_WPH + (size_t)1280*ND*2;
static const size_t OFF_SC  = OFF_WPL + (size_t)1280*ND*2;
static const size_t OFF_SH  = OFF_SC  + (size_t)ND*4;
static const size_t OFF_RM  = OFF_SH  + (size_t)ND*4;
static const size_t OFF_RI  = OFF_RM  + (size_t)NB*4;
static const size_t OFF_HA  = OFF_RI  + (size_t)NB*4;
static const size_t OFF_RU  = OFF_HA  + (size_t)NB*4;

__device__ __forceinline__ float uh2f(ushort u) {
    _Float16 h = __builtin_bit_cast(_Float16, u);
    return (float)h;
}
__device__ __forceinline__ ushort f2uh(float f) {
    _Float16 h = (_Float16)f;
    return __builtin_bit_cast(ushort, h);
}
__device__ __forceinline__ void load_lds16(const void* g, void* l) {
    __builtin_amdgcn_global_load_lds((const __attribute__((address_space(1))) void*)g,
                                     (__attribute__((address_space(3))) void*)l, 16, 0, 0);
}

// ---------------- split fp32 x -> (hi, lo) f16 planes ----------------
__global__ void k_split(const float* __restrict__ x, ushort* __restrict__ hi, ushort* __restrict__ lo)
{
    size_t i = ((size_t)blockIdx.x * 256 + threadIdx.x) * 4;
    float4 v = *(const float4*)(x + i);
    ushort4 h, l;
    h.x = f2uh(v.x); l.x = f2uh(v.x - uh2f(h.x));
    h.y = f2uh(v.y); l.y = f2uh(v.y - uh2f(h.y));
    h.z = f2uh(v.z); l.z = f2uh(v.z - uh2f(h.z));
    h.w = f2uh(v.w); l.w = f2uh(v.w - uh2f(h.w));
    *(ushort4*)(hi + i) = h;
    *(ushort4*)(lo + i) = l;
}

// ---------------- init: pack W (hi/lo, [dout][t][din]), BN affine, q, halted, running ----
__global__ void k_init(const float* __restrict__ conv_w, const float* __restrict__ conv_b,
                       const float* __restrict__ bn_gamma, const float* __restrict__ bn_beta,
                       const float* __restrict__ bn_mean, const float* __restrict__ bn_var,
                       const float* __restrict__ query,
                       ushort* __restrict__ Wph, ushort* __restrict__ Wpl,
                       float* __restrict__ scale, float* __restrict__ shift,
                       float* __restrict__ q, int* __restrict__ halted, int* __restrict__ running)
{
    int idx = blockIdx.x * 256 + threadIdx.x;
    if (idx < 1280 * 256) {
        int din  = idx & 255;
        int r    = idx >> 8;
        int t    = r % 5;
        int dout = r / 5;
        float w = conv_w[dout * 1280 + din * 5 + t];
        ushort wh = f2uh(w);
        Wph[idx] = wh;
        Wpl[idx] = f2uh(w - uh2f(wh));
    }
    if (idx < NB * ND) q[idx] = query[idx & (ND - 1)];
    if (idx < ND) {
        float a = bn_gamma[idx] * rsqrtf(bn_var[idx] + EPSBN);
        scale[idx] = a;
        shift[idx] = (conv_b[idx] - bn_mean[idx]) * a + bn_beta[idx];
    }
    if (idx < NB) halted[idx] = 0;
    if (idx == 0) running[0] = 1;
}

// ---------------- K1: e[b,s] = dot(x[b,s,:], q[b,:]) (hi+lo), mask -> -inf ----------------
__global__ void k_attn(const ushort* __restrict__ xhi, const ushort* __restrict__ xlo,
                       const float* __restrict__ q, const int* __restrict__ mask,
                       float* __restrict__ e)
{
    int row  = blockIdx.x * 4 + (threadIdx.x >> 6);
    int lane = threadIdx.x & 63;
    int b    = row >> 12;
    size_t o = (size_t)row * ND + (lane << 2);
    ushort4 hv = *(const ushort4*)(xhi + o);
    ushort4 lv = *(const ushort4*)(xlo + o);
    float4 qv = *(const float4*)(q + b * ND + (lane << 2));
    float v = (uh2f(hv.x) + uh2f(lv.x)) * qv.x
            + (uh2f(hv.y) + uh2f(lv.y)) * qv.y
            + (uh2f(hv.z) + uh2f(lv.z)) * qv.z
            + (uh2f(hv.w) + uh2f(lv.w)) * qv.w;
    #pragma unroll
    for (int off = 32; off; off >>= 1) v += __shfl_xor(v, off, 64);
    if (lane == 0) e[row] = (mask[row] != 0) ? -INFINITY : v;
}

// ---------------- K2: per-b softmax stats; block0 computes running flag ----------------
__global__ void k_stats(const float* __restrict__ e, float* __restrict__ rmax,
                        float* __restrict__ rinv, const int* __restrict__ halted,
                        int* __restrict__ running)
{
    __shared__ float sm[256];
    int b = blockIdx.x, tid = threadIdx.x;
    float m = -INFINITY;
    for (int s = tid; s < NS; s += 256) m = fmaxf(m, e[b * NS + s]);
    sm[tid] = m; __syncthreads();
    for (int off = 128; off; off >>= 1) {
        if (tid < off) sm[tid] = fmaxf(sm[tid], sm[tid + off]);
        __syncthreads();
    }
    float bm = sm[0]; __syncthreads();
    float sum = 0.f;
    for (int s = tid; s < NS; s += 256) sum += expf(e[b * NS + s] - bm);
    sm[tid] = sum; __syncthreads();
    for (int off = 128; off; off >>= 1) {
        if (tid < off) sm[tid] += sm[tid + off];
        __syncthreads();
    }
    if (tid == 0) { rmax[b] = bm; rinv[b] = 1.0f / sm[0]; }
    if (b == 0 && tid < 64) {
        unsigned long long any = __ballot(tid < NB && halted[tid] != 0);
        if (tid == 0) running[0] = (any == 0ull) ? 1 : 0;
    }
}

// ---------------- K3: conv via split-f16 MFMA + BN + leakyReLU + mask -------------------
// block 256 thr = 4 waves; tile BM=128 rows x BN=256 douts; wave = 128 rows x 64 douts
// (M_rep=8, N_rep=4 of 16x16x32); K = 5 taps x 256 din, din chunked by 64 into LDS.
__global__ __launch_bounds__(256, 2) void k_conv(
    const ushort* __restrict__ xhi, const ushort* __restrict__ xlo,
    ushort* __restrict__ ohi, ushort* __restrict__ olo,
    const ushort* __restrict__ Wph, const ushort* __restrict__ Wpl,
    const float* __restrict__ scale, const float* __restrict__ shift,
    const int* __restrict__ maskp, const int* __restrict__ running)
{
    const int bb  = blockIdx.x >> 5;
    const int s0  = (blockIdx.x & 31) << 7;
    const int tid = threadIdx.x;

    if (running[0] == 0) {   // frozen: copy state
        const size_t base = ((size_t)bb * NS + s0) * ND;
        const uint4* sh_ = (const uint4*)(xhi + base);
        const uint4* sl_ = (const uint4*)(xlo + base);
        uint4* dh = (uint4*)(ohi + base);
        uint4* dl = (uint4*)(olo + base);
        for (int i = tid; i < 4096; i += 256) { dh[i] = sh_[i]; dl[i] = sl_[i]; }
        return;
    }

    __shared__ __align__(16) ushort Ah[8704];   // 136 rows x 64 din (rows s0-2 .. s0+133)
    __shared__ __align__(16) ushort Al[8704];

    const int lane  = tid & 63;
    const int wid   = tid >> 6;
    const int mlane = lane & 15;       // C col / A row / B col lane
    const int klane = lane >> 4;       // k-block
    const int dbase = wid << 6;        // wave's dout base

    floatx4 acc[8][4];
    #pragma unroll
    for (int m = 0; m < 8; ++m)
        #pragma unroll
        for (int n = 0; n < 4; ++n) acc[m][n] = (floatx4){0.f, 0.f, 0.f, 0.f};

    const bool ztop = (s0 == 0), zbot = (s0 == NS - 128);

    for (int kc = 0; kc < 4; ++kc) {
        __syncthreads();   // LDS reuse protection across chunks
        // stage 136 rows x 64 din, both splits; LDS linear dest, pre-swizzled global src
        for (int i0 = tid; i0 < 1088; i0 += 256) {
            int lrow = i0 >> 3;
            int grp  = (i0 & 7) ^ (lrow & 7);
            int srow = s0 - 2 + lrow;
            srow = srow < 0 ? 0 : (srow > NS - 1 ? NS - 1 : srow);
            size_t go = ((size_t)bb * NS + srow) * ND + (kc << 6) + (grp << 3);
            load_lds16(xhi + go, &Ah[i0 * 8]);
            load_lds16(xlo + go, &Al[i0 * 8]);
        }
        __syncthreads();   // compiler drains vmcnt before barrier
        if (ztop || zbot) {
            if (ztop && tid < 32) {   // rows 0,1 <- global rows -2,-1 := 0
                *(unsigned long long*)(&Ah[tid * 4]) = 0ull;
                *(unsigned long long*)(&Al[tid * 4]) = 0ull;
            }
            if (zbot && tid < 32) {   // rows 130,131 <- global rows 4096,4097 := 0
                *(unsigned long long*)(&Ah[8320 + tid * 4]) = 0ull;
                *(unsigned long long*)(&Al[8320 + tid * 4]) = 0ull;
            }
            __syncthreads();
        }

        #pragma unroll
        for (int t = 0; t < 5; ++t) {
            #pragma unroll
            for (int ds_ = 0; ds_ < 2; ++ds_) {
                // B fragments: W[k = (t, din..din+7)][dout], 8 consecutive din per lane
                half8 bh[4], bl[4];
                const int din = (kc << 6) + (ds_ << 5) + (klane << 3);
                #pragma unroll
                for (int n = 0; n < 4; ++n) {
                    size_t wo = ((size_t)((dbase + (n << 4) + mlane) * 5 + t) << 8) + din;
                    bh[n] = *(const half8*)(Wph + wo);
                    bl[n] = *(const half8*)(Wpl + wo);
                }
                const int gb = (ds_ << 2) + klane;   // 16B group within 64-din row
                #pragma unroll
                for (int m = 0; m < 8; ++m) {
                    int row = (m << 4) + mlane + t;              // lds row = out_row + t
                    int off = (row << 7) + ((gb ^ (row & 7)) << 4);
                    half8 ah = *(const half8*)((const char*)Ah + off);
                    half8 al = *(const half8*)((const char*)Al + off);
                    #pragma unroll
                    for (int n = 0; n < 4; ++n) {
                        acc[m][n] = __builtin_amdgcn_mfma_f32_16x16x32_f16(ah, bh[n], acc[m][n], 0, 0, 0);
                        acc[m][n] = __builtin_amdgcn_mfma_f32_16x16x32_f16(ah, bl[n], acc[m][n], 0, 0, 0);
                        acc[m][n] = __builtin_amdgcn_mfma_f32_16x16x32_f16(al, bh[n], acc[m][n], 0, 0, 0);
                    }
                }
            }
        }
    }

    // epilogue: BN + leakyReLU + mask, emit split f16
    float sc[4], sh[4];
    #pragma unroll
    for (int n = 0; n < 4; ++n) {
        int d = dbase + (n << 4) + mlane;
        sc[n] = scale[d]; sh[n] = shift[d];
    }
    #pragma unroll
    for (int m = 0; m < 8; ++m) {
        #pragma unroll
        for (int r = 0; r < 4; ++r) {
            int s = s0 + (m << 4) + (klane << 2) + r;      // C/D: row=(lane>>4)*4+reg
            int mk = maskp[bb * NS + s];
            size_t ob = ((size_t)bb * NS + s) * ND + dbase + mlane;
            #pragma unroll
            for (int n = 0; n < 4; ++n) {
                float v = acc[m][n][r] * sc[n] + sh[n];
                v = (v >= 0.f) ? v : NEG_SLOPE * v;
                v = mk ? 0.f : v;
                ushort h = f2uh(v);
                ushort l = f2uh(v - uh2f(h));
                ohi[ob + (size_t)(n << 4)] = h;
                olo[ob + (size_t)(n << 4)] = l;
            }
        }
    }
}

// ---------------- K4: o partials over 128-row chunks ----------------
__global__ void k_opart(const ushort* __restrict__ xhi, const ushort* __restrict__ xlo,
                        const float* __restrict__ e, const float* __restrict__ rmax,
                        const float* __restrict__ rinv, float* __restrict__ o_part)
{
    int b = blockIdx.x >> 5, ch = blockIdx.x & 31;
    int s0 = ch << 7;
    int tid = threadIdx.x;
    __shared__ float p[128];
    if (tid < 128) {
        float ev = e[b * NS + s0 + tid];
        p[tid] = expf(ev - rmax[b]) * rinv[b];
    }
    __syncthreads();
    float acc = 0.f;
    const ushort* hp = xhi + ((size_t)b * NS + s0) * ND + tid;
    const ushort* lp = xlo + ((size_t)b * NS + s0) * ND + tid;
    #pragma unroll 4
    for (int j = 0; j < 128; ++j)
        acc += p[j] * (uh2f(hp[(size_t)j * ND]) + uh2f(lp[(size_t)j * ND]));
    o_part[(b * 32 + ch) * ND + tid] = acc;
}

// ---------------- K5: reduce o, halt logits, gated q/halted update ----------------
__global__ void k_update(const float* __restrict__ o_part, float* __restrict__ q,
                         const float* __restrict__ halt_w, const float* __restrict__ halt_b,
                         int* __restrict__ halted, const int* __restrict__ running)
{
    int b = blockIdx.x, d = threadIdx.x;
    __shared__ float sh0[256], sh1[256];
    float o = 0.f;
    #pragma unroll
    for (int ch = 0; ch < 32; ++ch) o += o_part[(b * 32 + ch) * ND + d];
    float qd = q[b * ND + d];
    float s1 = o + qd;
    sh0[d] = s1 * halt_w[d];
    sh1[d] = s1 * halt_w[ND + d];
    __syncthreads();
    for (int off = 128; off; off >>= 1) {
        if (d < off) { sh0[d] += sh0[d + off]; sh1[d] += sh1[d + off]; }
        __syncthreads();
    }
    float l0 = sh0[0] + halt_b[0];
    float l1 = sh1[0] + halt_b[1];
    int hOld = halted[b];
    if (running[0]) {
        q[b * ND + d] = o + qd * (1.f - (float)hOld);
        if (d == 0) halted[b] = hOld | ((l1 > l0) ? 1 : 0);
    }
}

// ---------------- K6: q -> d_out ----------------
__global__ void k_copyout(const float* __restrict__ q, float* __restrict__ out)
{
    int idx = blockIdx.x * 256 + threadIdx.x;
    if (idx < NB * ND) out[idx] = q[idx];
}

extern "C" void kernel_launch(void* const* d_in, const int* in_sizes, int n_in,
                              void* d_out, int out_size, void* d_ws, size_t ws_size,
                              hipStream_t stream)
{
    const float* x        = (const float*)d_in[0];
    const int*   mask     = (const int*)  d_in[1];
    const float* query    = (const float*)d_in[2];
    const float* conv_w   = (const float*)d_in[3];
    const float* conv_b   = (const float*)d_in[4];
    const float* bn_gamma = (const float*)d_in[5];
    const float* bn_beta  = (const float*)d_in[6];
    const float* bn_mean  = (const float*)d_in[7];
    const float* bn_var   = (const float*)d_in[8];
    const float* halt_w   = (const float*)d_in[9];
    const float* halt_b   = (const float*)d_in[10];

    char* ws = (char*)d_ws;
    ushort* hi0 = (ushort*)(ws + OFF_HI0);
    ushort* lo0 = (ushort*)(ws + OFF_LO0);
    ushort* hi1 = (ushort*)(ws + OFF_HI1);
    ushort* lo1 = (ushort*)(ws + OFF_LO1);
    float* ebuf = (float*)(ws + OFF_E);
    float* qbuf = (float*)(ws + OFF_Q);
    float* opart= (float*)(ws + OFF_OP);
    ushort* Wph = (ushort*)(ws + OFF_WPH);
    ushort* Wpl = (ushort*)(ws + OFF_WPL);
    float* scale= (float*)(ws + OFF_SC);
    float* shift= (float*)(ws + OFF_SH);
    float* rmax = (float*)(ws + OFF_RM);
    float* rinv = (float*)(ws + OFF_RI);
    int* halted = (int*)  (ws + OFF_HA);
    int* runf   = (int*)  (ws + OFF_RU);

    k_init<<<1280, 256, 0, stream>>>(conv_w, conv_b, bn_gamma, bn_beta, bn_mean, bn_var,
                                     query, Wph, Wpl, scale, shift, qbuf, halted, runf);
    k_split<<<32768, 256, 0, stream>>>(x, hi0, lo0);

    for (int h = 0; h < NHOP; ++h) {
        const ushort* ih = (h & 1) ? hi1 : hi0;
        const ushort* il = (h & 1) ? lo1 : lo0;
        ushort* oh = (h & 1) ? hi0 : hi1;
        ushort* ol = (h & 1) ? lo0 : lo1;

        k_attn  <<<NB * NS / 4, 256, 0, stream>>>(ih, il, qbuf, mask, ebuf);
        k_stats <<<NB, 256, 0, stream>>>(ebuf, rmax, rinv, halted, runf);
        k_conv  <<<NB * 32, 256, 0, stream>>>(ih, il, oh, ol, Wph, Wpl, scale, shift, mask, runf);
        k_opart <<<NB * 32, 256, 0, stream>>>(oh, ol, ebuf, rmax, rinv, opart);
        k_update<<<NB, 256, 0, stream>>>(opart, qbuf, halt_w, halt_b, halted, runf);
    }

    k_copyout<<<NB, 256, 0, stream>>>(qbuf, (float*)d_out);
}